// Round 17
// baseline (71.291 us; speedup 1.0000x reference)
//
#include <hip/hip_runtime.h>
#include <hip/hip_bf16.h>

constexpr int HID = 1024;
constexpr int KD  = 16;    // probe directions
constexpr int TM  = 16;    // rows per tile
constexpr int NW  = 16;    // waves per block (each owns a 64-wide col slice)

typedef short bf16x8 __attribute__((ext_vector_type(8)));   // MFMA A/B frag
typedef float f32x4  __attribute__((ext_vector_type(4)));   // MFMA C/D frag

__device__ __forceinline__ short f2b(float x) {
    __hip_bfloat16 b = __float2bfloat16(x);
    return *reinterpret_cast<short*>(&b);
}
__device__ __forceinline__ float b2f(short s) {
    return __uint_as_float(((unsigned int)(unsigned short)s) << 16);
}

// Wave w owns cols [w*64, w*64+64). Chunk p=0,1: gb = w*64 + p*32.
// Qt[r][k] = bf16(Q[k][r]) (16x1024): coef B-frags, 16B contiguous reads.
// Qa permuted (64x16x16): jslot = w*4 + jl (jl=0..3), p=jl>>1, odd=jl&1,
//   col(jslot, rr) = w*64 + p*32 + (rr>>2)*8 + odd*4 + (rr&3)
// -> epilogue MFMA's D-layout lands exactly on the coef A-frag registers
//    (same verified R13 scheme, w-scale 256 -> 64, pairs 8 -> 2).
__global__ void q_setup(const float* __restrict__ Qf,
                        short* __restrict__ Qt, short* __restrict__ Qa) {
    const int idx = blockIdx.x*256 + threadIdx.x;
    if (idx < 16*HID) {
        const int r = idx >> 10, k = idx & 1023;
        Qt[idx] = f2b(Qf[k*KD + r]);
        const int gs = idx >> 4, dir = idx & 15;
        const int jslot = gs >> 4, rr = gs & 15;
        const int w = jslot >> 2, jl = jslot & 3;
        const int p = jl >> 1, odd = jl & 1;
        const int col = w*64 + p*32 + (rr >> 2)*8 + odd*4 + (rr & 3);
        Qa[idx] = f2b(Qf[col*KD + dir]);
    }
}

// 16 waves/block, 64 cols/wave: persistent Q = 24 VGPR -> whole kernel fits
// the <=64-VGPR / 8-waves-per-SIMD tier WITH Q register-resident (R13-R16
// post-mortems: Q persistence and 8 waves/SIMD were mutually exclusive at
// 128+ cols/wave). 2048 independent blocks, ONE barrier, fused epilogue.
__global__ __launch_bounds__(NW*64)
void probe_removal_w16(const float* __restrict__ H,
                       const short* __restrict__ Qt,
                       const short* __restrict__ Qa,
                       float* __restrict__ out)
{
    const int lane = threadIdx.x & 63;
    const int w    = threadIdx.x >> 6;   // wave 0..15
    const int r    = lane & 15;
    const int q    = lane >> 4;
    const int tile = blockIdx.x;

    __shared__ __align__(16) float ctr[NW][TM][20];  // 20.5 KB coef partials
    __shared__ float s2p[NW][TM];                    // 1 KB ||h||^2 partials

    const float* hrow = H + (size_t)tile*TM*HID + r*HID;
    const int    cb   = w*64 + q*8;      // lane's column base

    // ---- persistent Q fragments (24 VGPR total) ----
    const bf16x8 bq0 = *reinterpret_cast<const bf16x8*>(Qt + r*1024 + cb);
    const bf16x8 bq1 = *reinterpret_cast<const bf16x8*>(Qt + r*1024 + cb + 32);
    bf16x8 aq00, aq01, aq10, aq11;       // epilogue A-frags (pairs p=0,1)
    if (q < 2) {
        aq00 = *reinterpret_cast<const bf16x8*>(Qa + ((w*4 + 0)*16 + r)*KD + q*8);
        aq01 = *reinterpret_cast<const bf16x8*>(Qa + ((w*4 + 1)*16 + r)*KD + q*8);
        aq10 = *reinterpret_cast<const bf16x8*>(Qa + ((w*4 + 2)*16 + r)*KD + q*8);
        aq11 = *reinterpret_cast<const bf16x8*>(Qa + ((w*4 + 3)*16 + r)*KD + q*8);
    } else {
        #pragma unroll
        for (int i = 0; i < 8; ++i) { aq00[i]=0; aq01[i]=0; aq10[i]=0; aq11[i]=0; }
    }

    // ---- coef GEMM: 4 independent float4 loads issued up-front ----
    const float4 x0 = *reinterpret_cast<const float4*>(hrow + cb);
    const float4 y0 = *reinterpret_cast<const float4*>(hrow + cb + 4);
    const float4 x1 = *reinterpret_cast<const float4*>(hrow + cb + 32);
    const float4 y1 = *reinterpret_cast<const float4*>(hrow + cb + 36);

    float s2 = 0.f;
    s2 = fmaf(x0.x,x0.x, fmaf(x0.y,x0.y, fmaf(x0.z,x0.z, fmaf(x0.w,x0.w, s2))));
    s2 = fmaf(y0.x,y0.x, fmaf(y0.y,y0.y, fmaf(y0.z,y0.z, fmaf(y0.w,y0.w, s2))));
    s2 = fmaf(x1.x,x1.x, fmaf(x1.y,x1.y, fmaf(x1.z,x1.z, fmaf(x1.w,x1.w, s2))));
    s2 = fmaf(y1.x,y1.x, fmaf(y1.y,y1.y, fmaf(y1.z,y1.z, fmaf(y1.w,y1.w, s2))));

    bf16x8 af0, af1;
    af0[0]=f2b(x0.x); af0[1]=f2b(x0.y); af0[2]=f2b(x0.z); af0[3]=f2b(x0.w);
    af0[4]=f2b(y0.x); af0[5]=f2b(y0.y); af0[6]=f2b(y0.z); af0[7]=f2b(y0.w);
    af1[0]=f2b(x1.x); af1[1]=f2b(x1.y); af1[2]=f2b(x1.z); af1[3]=f2b(x1.w);
    af1[4]=f2b(y1.x); af1[5]=f2b(y1.y); af1[6]=f2b(y1.z); af1[7]=f2b(y1.w);

    f32x4 acc = {0.f,0.f,0.f,0.f};
    acc = __builtin_amdgcn_mfma_f32_16x16x32_bf16(af0, bq0, acc, 0, 0, 0);
    acc = __builtin_amdgcn_mfma_f32_16x16x32_bf16(af1, bq1, acc, 0, 0, 0);

    s2 += __shfl_xor(s2, 16);            // combine q-groups -> row-r partial
    s2 += __shfl_xor(s2, 32);

    #pragma unroll
    for (int i = 0; i < 4; ++i) ctr[w][q*4 + i][r] = acc[i];   // C[row q*4+i][dir r]
    if (q == 0) s2p[w][r] = s2;

    __syncthreads();   // the ONLY barrier

    // ---- reduce over 16 waves -> coefs for row r, scale ----
    float cf[8] = {0,0,0,0,0,0,0,0};
    if (q < 2) {
        #pragma unroll
        for (int w2 = 0; w2 < NW; ++w2) {
            const float4 a = *reinterpret_cast<const float4*>(&ctr[w2][r][q*8]);
            const float4 b = *reinterpret_cast<const float4*>(&ctr[w2][r][q*8 + 4]);
            cf[0]+=a.x; cf[1]+=a.y; cf[2]+=a.z; cf[3]+=a.w;
            cf[4]+=b.x; cf[5]+=b.y; cf[6]+=b.z; cf[7]+=b.w;
        }
    }
    float s2tot = 0.f;
    #pragma unroll
    for (int w2 = 0; w2 < NW; ++w2) s2tot += s2p[w2][r];   // broadcast reads

    float sc2 = 0.f;
    #pragma unroll
    for (int i = 0; i < 8; ++i) sc2 = fmaf(cf[i], cf[i], sc2);
    sc2 += __shfl_xor(sc2, 16);
    sc2 += __shfl_xor(sc2, 32);
    const float scale = rsqrtf(fmaxf(1.0f - sc2 / s2tot, 1e-20f));

    bf16x8 pb;   // B[k=dir][n=row r]; q>=2 lanes carry the K-pad zeros
    #pragma unroll
    for (int i = 0; i < 8; ++i) pb[i] = f2b(cf[i]);

    // ---- fused epilogue: h from af registers; 4 stores per lane ----
    float* orow = out + (size_t)tile*TM*HID + r*HID;
    const f32x4 zero4 = {0.f,0.f,0.f,0.f};

    const f32x4 d00 = __builtin_amdgcn_mfma_f32_16x16x32_bf16(aq00, pb, zero4, 0, 0, 0);
    const f32x4 d01 = __builtin_amdgcn_mfma_f32_16x16x32_bf16(aq01, pb, zero4, 0, 0, 0);
    const f32x4 d10 = __builtin_amdgcn_mfma_f32_16x16x32_bf16(aq10, pb, zero4, 0, 0, 0);
    const f32x4 d11 = __builtin_amdgcn_mfma_f32_16x16x32_bf16(aq11, pb, zero4, 0, 0, 0);

    f32x4 o00, o01, o10, o11;
    #pragma unroll
    for (int ii = 0; ii < 4; ++ii) {
        o00[ii] = (b2f(af0[ii])     - d00[ii]) * scale;
        o01[ii] = (b2f(af0[4 + ii]) - d01[ii]) * scale;
        o10[ii] = (b2f(af1[ii])     - d10[ii]) * scale;
        o11[ii] = (b2f(af1[4 + ii]) - d11[ii]) * scale;
    }
    // 4 q-lanes x 8 floats cover each 128B line completely
    *reinterpret_cast<f32x4*>(orow + cb)          = o00;
    *reinterpret_cast<f32x4*>(orow + cb + 4)      = o01;
    *reinterpret_cast<f32x4*>(orow + cb + 32)     = o10;
    *reinterpret_cast<f32x4*>(orow + cb + 36)     = o11;
}

extern "C" void kernel_launch(void* const* d_in, const int* in_sizes, int n_in,
                              void* d_out, int out_size, void* d_ws, size_t ws_size,
                              hipStream_t stream) {
    const float* H  = (const float*)d_in[0];   // [8,4096,1024] f32
    const float* Qf = (const float*)d_in[1];   // [1024,16] f32, orthonormal cols
    float* outp     = (float*)d_out;
    const int nrows  = in_sizes[0] / HID;      // 32768
    const int ntiles = nrows / TM;             // 2048

    short* Qt = (short*)d_ws;                  // 32 KB
    short* Qa = Qt + 16*HID;                   // 32 KB (permuted)

    hipLaunchKernelGGL(q_setup, dim3(64), dim3(256), 0, stream, Qf, Qt, Qa);

    // 2048 independent 16-wave blocks; ~22KB LDS -> 2 blocks/CU, 32 waves/CU
    hipLaunchKernelGGL(probe_removal_w16, dim3(ntiles), dim3(NW*64), 0, stream,
                       H, Qt, Qa, outp);
}

// Round 18
// 51.056 us; speedup vs baseline: 1.3963x; 1.3963x over previous
//
#include <hip/hip_runtime.h>
#include <hip/hip_bf16.h>

constexpr int HID = 1024;
constexpr int KD  = 16;    // probe directions
constexpr int TM  = 16;    // rows per tile
constexpr int NW  = 8;     // waves per block (each owns a 128-wide col slice)
constexpr int TPB = 8;     // tiles per block (2048 tiles / 256 blocks)

typedef short bf16x8 __attribute__((ext_vector_type(8)));   // MFMA A/B frag
typedef float f32x4  __attribute__((ext_vector_type(4)));   // MFMA C/D frag

__device__ __forceinline__ short f2b(float x) {
    __hip_bfloat16 b = __float2bfloat16(x);
    return *reinterpret_cast<short*>(&b);
}
__device__ __forceinline__ float b2f(short s) {
    return __uint_as_float(((unsigned int)(unsigned short)s) << 16);
}

#define SCHED_FENCE() __builtin_amdgcn_sched_barrier(0)

// Stage one 64KB H tile via global_load_lds: wave w stages rows w*2..w*2+1.
// 16B-piece swizzle ^ (row&7) applied on the GLOBAL source address (LDS dest
// linear, as required); coef ds_read applies the same XOR.
__device__ __forceinline__ void stage_tile(float* ldsBuf, const float* Hbase,
                                           int w, int lane) {
    #pragma unroll
    for (int i = 0; i < 8; ++i) {
        const int rr = w*2 + (i >> 2);
        const int qq = i & 3;
        const int s  = qq*64 + lane;                  // lds piece slot
        const float* g = Hbase + rr*1024 + ((s ^ (rr & 7)) << 2);
        const float* l = ldsBuf + rr*1024 + qq*256;   // wave-uniform base; HW adds lane*16
        __builtin_amdgcn_global_load_lds(
            (const __attribute__((address_space(1))) void*)g,
            (__attribute__((address_space(3))) void*)l, 16, 0, 0);
    }
}

// R18 = R15 (best structure, 57.9 us) with the q_setup pre-kernel REMOVED:
// rounds 13-16 all plateaued at ~58 us across four different structures; the
// shared residual cost is the serialized two-kernel launch (~5-8 us). Each
// block now gathers its 56 persistent Q-fragment registers directly from the
// 64KB L2-hot Qf at block start (amortized over 8 tiles).
__global__ __launch_bounds__(NW*64)
void probe_removal_one(const float* __restrict__ H,
                       const float* __restrict__ Qf,
                       float* __restrict__ out)
{
    const int lane = threadIdx.x & 63;
    const int w    = threadIdx.x >> 6;   // wave: col slice [w*128, w*128+128)
    const int r    = lane & 15;
    const int q    = lane >> 4;

    __shared__ __align__(16) float Hb[2][TM][HID];   // 128 KB double buffer
    __shared__ __align__(16) float ctr[NW][TM][20];  // coef partials
    __shared__ float s2p[NW][TM];

    const int tile0 = blockIdx.x * TPB;

    // ---- persistent Q fragments gathered directly from Qf (no workspace) ----
    // coef B-frag: bq[kt][i] = bf16(Q[k][r]), k = w*128 + kt*32 + q*8 + i
    bf16x8 bq[4];
    #pragma unroll
    for (int kt = 0; kt < 4; ++kt)
        #pragma unroll
        for (int i = 0; i < 8; ++i)
            bq[kt][i] = f2b(Qf[(w*128 + kt*32 + q*8 + i)*KD + r]);
    // epilogue A-frags (R13-verified permutation, R15 geometry):
    // pair p: col0 = w*128 + p*32 + (r>>2)*8 + (r&3), col1 = col0 + 4;
    // aq0[p][i] = bf16(Q[col0][q*8+i]) -> two contiguous float4 loads each.
    bf16x8 aq0[4], aq1[4];
    #pragma unroll
    for (int p = 0; p < 4; ++p) {
        if (q < 2) {
            const int col0 = w*128 + p*32 + ((r >> 2) << 3) + (r & 3);
            const float* s0 = Qf + col0*KD + q*8;
            const float* s1 = Qf + (col0 + 4)*KD + q*8;
            const float4 x0 = *reinterpret_cast<const float4*>(s0);
            const float4 y0 = *reinterpret_cast<const float4*>(s0 + 4);
            const float4 x1 = *reinterpret_cast<const float4*>(s1);
            const float4 y1 = *reinterpret_cast<const float4*>(s1 + 4);
            aq0[p][0]=f2b(x0.x); aq0[p][1]=f2b(x0.y); aq0[p][2]=f2b(x0.z); aq0[p][3]=f2b(x0.w);
            aq0[p][4]=f2b(y0.x); aq0[p][5]=f2b(y0.y); aq0[p][6]=f2b(y0.z); aq0[p][7]=f2b(y0.w);
            aq1[p][0]=f2b(x1.x); aq1[p][1]=f2b(x1.y); aq1[p][2]=f2b(x1.z); aq1[p][3]=f2b(x1.w);
            aq1[p][4]=f2b(y1.x); aq1[p][5]=f2b(y1.y); aq1[p][6]=f2b(y1.z); aq1[p][7]=f2b(y1.w);
        } else {
            #pragma unroll
            for (int i = 0; i < 8; ++i) { aq0[p][i] = 0; aq1[p][i] = 0; }
        }
    }
    SCHED_FENCE();

    // ---- prologue: stage tiles 0 and 1 (8 loads each per wave) ----
    stage_tile(&Hb[0][0][0], H + (size_t)tile0*TM*HID, w, lane);
    SCHED_FENCE();
    stage_tile(&Hb[1][0][0], H + (size_t)(tile0+1)*TM*HID, w, lane);
    SCHED_FENCE();
    asm volatile("s_waitcnt vmcnt(8)" ::: "memory");   // tile 0 landed (tile 1 in flight)
    SCHED_FENCE();
    __builtin_amdgcn_s_barrier();

    #pragma unroll
    for (int t = 0; t < TPB; ++t) {
        const int cur = t & 1;
        const char* HbC = (const char*)&Hb[cur][0][0];

        // ---- coef GEMM from LDS (swizzled b128 reads); af = h slice in regs ----
        bf16x8 af[4];
        f32x4 acc0 = {0.f,0.f,0.f,0.f}, acc1 = {0.f,0.f,0.f,0.f};
        float s2 = 0.f;
        #pragma unroll
        for (int kt = 0; kt < 4; ++kt) {
            const int P  = w*32 + kt*8 + q*2;       // even piece index
            const int sx = P ^ (r & 7);
            const float4 x = *(const float4*)(HbC + r*4096 + sx*16);
            const float4 y = *(const float4*)(HbC + r*4096 + (sx^1)*16);
            s2 = fmaf(x.x,x.x, fmaf(x.y,x.y, fmaf(x.z,x.z, fmaf(x.w,x.w, s2))));
            s2 = fmaf(y.x,y.x, fmaf(y.y,y.y, fmaf(y.z,y.z, fmaf(y.w,y.w, s2))));
            bf16x8 a;
            a[0]=f2b(x.x); a[1]=f2b(x.y); a[2]=f2b(x.z); a[3]=f2b(x.w);
            a[4]=f2b(y.x); a[5]=f2b(y.y); a[6]=f2b(y.z); a[7]=f2b(y.w);
            af[kt] = a;
            if (kt & 1) acc1 = __builtin_amdgcn_mfma_f32_16x16x32_bf16(a, bq[kt], acc1, 0, 0, 0);
            else        acc0 = __builtin_amdgcn_mfma_f32_16x16x32_bf16(a, bq[kt], acc0, 0, 0, 0);
        }
        const f32x4 acc = acc0 + acc1;
        s2 += __shfl_xor(s2, 16);
        s2 += __shfl_xor(s2, 32);

        #pragma unroll
        for (int i = 0; i < 4; ++i) ctr[w][q*4 + i][r] = acc[i];
        if (q == 0) s2p[w][r] = s2;

        // ctr visible to all waves; raw barrier does NOT drain vmcnt:
        asm volatile("s_waitcnt lgkmcnt(0)" ::: "memory");
        SCHED_FENCE();
        __builtin_amdgcn_s_barrier();
        SCHED_FENCE();

        // ---- stage tile t+2 into the freed buffer ----
        if (t + 2 < TPB)
            stage_tile(&Hb[cur][0][0], H + (size_t)(tile0+t+2)*TM*HID, w, lane);
        SCHED_FENCE();

        // ---- cross-wave reduce -> coefs, scale, pb ----
        float cf[8] = {0,0,0,0,0,0,0,0};
        if (q < 2) {
            #pragma unroll
            for (int w2 = 0; w2 < NW; ++w2) {
                const float4 a = *reinterpret_cast<const float4*>(&ctr[w2][r][q*8]);
                const float4 b = *reinterpret_cast<const float4*>(&ctr[w2][r][q*8 + 4]);
                cf[0]+=a.x; cf[1]+=a.y; cf[2]+=a.z; cf[3]+=a.w;
                cf[4]+=b.x; cf[5]+=b.y; cf[6]+=b.z; cf[7]+=b.w;
            }
        }
        float s2tot = 0.f;
        #pragma unroll
        for (int w2 = 0; w2 < NW; ++w2) s2tot += s2p[w2][r];

        float sc2 = 0.f;
        #pragma unroll
        for (int i = 0; i < 8; ++i) sc2 = fmaf(cf[i], cf[i], sc2);
        sc2 += __shfl_xor(sc2, 16);
        sc2 += __shfl_xor(sc2, 32);
        const float scale = rsqrtf(fmaxf(1.0f - sc2 / s2tot, 1e-20f));

        bf16x8 pb;
        #pragma unroll
        for (int i = 0; i < 8; ++i) pb[i] = f2b(cf[i]);

        // ---- fused epilogue: all operands in registers; 8 stores per lane ----
        float* orow = out + (size_t)(tile0+t)*TM*HID + r*HID + w*128;
        const f32x4 zero4 = {0.f,0.f,0.f,0.f};
        #pragma unroll
        for (int p = 0; p < 4; ++p) {
            const f32x4 d0 = __builtin_amdgcn_mfma_f32_16x16x32_bf16(aq0[p], pb, zero4, 0, 0, 0);
            const f32x4 d1 = __builtin_amdgcn_mfma_f32_16x16x32_bf16(aq1[p], pb, zero4, 0, 0, 0);
            f32x4 o0, o1;
            #pragma unroll
            for (int ii = 0; ii < 4; ++ii) {
                o0[ii] = (b2f(af[p][ii])     - d0[ii]) * scale;
                o1[ii] = (b2f(af[p][4 + ii]) - d1[ii]) * scale;
            }
            *reinterpret_cast<f32x4*>(orow + p*32 + q*8)     = o0;
            *reinterpret_cast<f32x4*>(orow + p*32 + q*8 + 4) = o1;
        }
        SCHED_FENCE();

        // ---- counted drain: stage(t+1) landed; stage(t+2)+stores(t) stay
        //      in flight (never vmcnt(0) mid-loop) ----
        if (t < TPB-1) {
            asm volatile("s_waitcnt vmcnt(16)" ::: "memory");
            SCHED_FENCE();
            __builtin_amdgcn_s_barrier();
            SCHED_FENCE();
        }
    }
}

extern "C" void kernel_launch(void* const* d_in, const int* in_sizes, int n_in,
                              void* d_out, int out_size, void* d_ws, size_t ws_size,
                              hipStream_t stream) {
    const float* H  = (const float*)d_in[0];   // [8,4096,1024] f32
    const float* Qf = (const float*)d_in[1];   // [1024,16] f32, orthonormal cols
    float* outp     = (float*)d_out;
    const int nrows  = in_sizes[0] / HID;      // 32768
    const int ntiles = nrows / TM;             // 2048

    // SINGLE launch: 139KB LDS -> 1 block/CU, 256 blocks x 8 tiles, DMA pipeline
    hipLaunchKernelGGL(probe_removal_one, dim3(ntiles / TPB), dim3(NW*64), 0, stream,
                       H, Qf, outp);
}